// Round 1
// baseline (391.724 us; speedup 1.0000x reference)
//
#include <hip/hip_runtime.h>

// ---------------- problem constants ----------------
#define EMBED 1024
#define NHEAD 16
#define HDIM  64
#define BATCH 2
#define SEQ   2048
#define ROWS  (BATCH*SEQ)   // 4096

typedef __bf16 bf16x8 __attribute__((ext_vector_type(8)));
typedef float  f32x4  __attribute__((ext_vector_type(4)));
typedef unsigned short u16x8 __attribute__((ext_vector_type(8)));
typedef unsigned short u16x4 __attribute__((ext_vector_type(4)));

__device__ __forceinline__ unsigned short f2bf(float f) {
    unsigned int u = __float_as_uint(f);
    u += 0x7FFFu + ((u >> 16) & 1u);          // round-to-nearest-even
    return (unsigned short)(u >> 16);
}
__device__ __forceinline__ f32x4 zero4() { f32x4 z = {0.f, 0.f, 0.f, 0.f}; return z; }

// ---------------- elementwise f32 -> bf16 cast (4M elements) ----------------
__global__ __launch_bounds__(256) void cvt_bf16_kernel(const float* __restrict__ in,
                                                       unsigned short* __restrict__ out) {
    int i = (blockIdx.x * 256 + threadIdx.x) * 4;
    float4 v = *(const float4*)(in + i);
    u16x4 o = {f2bf(v.x), f2bf(v.y), f2bf(v.z), f2bf(v.w)};
    *(u16x4*)(out + i) = o;
}

// ---------------- W [K,N] f32 -> Wt [N,K] bf16 (1024x1024) ----------------
__global__ __launch_bounds__(256) void transpose_cvt_kernel(const float* __restrict__ in,
                                                            unsigned short* __restrict__ out) {
    __shared__ float tile[32][33];
    int tx = threadIdx.x, ty = threadIdx.y;              // 32 x 8
    int x = blockIdx.x * 32 + tx;
    int y0 = blockIdx.y * 32 + ty;
#pragma unroll
    for (int r = 0; r < 4; ++r)
        tile[ty + 8 * r][tx] = in[(size_t)(y0 + 8 * r) * EMBED + x];
    __syncthreads();
    int ox = blockIdx.y * 32 + tx;                       // output col = input row
    int oy = blockIdx.x * 32 + ty;                       // output row = input col
#pragma unroll
    for (int r = 0; r < 4; ++r)
        out[(size_t)(oy + 8 * r) * EMBED + ox] = f2bf(tile[tx][ty + 8 * r]);
}

// ---------------- generic bf16 GEMM: C[M=4096,N=1024] = A[M,K=1024] * Bt[N,K]^T ----------------
// mode 0: out bf16 [B,H,S,HD]   (Q,K projections)
// mode 1: out bf16 [B,H,HD,S]   (V projection, pre-transposed for PV)
// mode 2: out f32  [M,N] = acc + bias + residual   (output projection)
__global__ __launch_bounds__(256, 2) void gemm_bt_kernel(const unsigned short* __restrict__ A,
                                                         const unsigned short* __restrict__ Bt,
                                                         const float* __restrict__ bias,
                                                         void* __restrict__ outp,
                                                         const float* __restrict__ residual,
                                                         int mode) {
    __shared__ unsigned short As[128 * 40];   // rows padded to 40 bf16 (80 B) -> ~2-way banks
    __shared__ unsigned short Bs[128 * 40];
    const int t = threadIdx.x;
    const int m0 = blockIdx.y * 128, n0 = blockIdx.x * 128;
    const int wave = t >> 6, lane = t & 63;
    const int wr = wave >> 1, wc = wave & 1;             // 2x2 wave grid, 64x64 each
    const int lm = lane & 15, lq = lane >> 4;
    const int srow = t >> 2, sc16 = t & 3;               // staging: 4 threads/row, 16B chunks

    f32x4 acc[4][4];
#pragma unroll
    for (int i = 0; i < 4; ++i)
#pragma unroll
        for (int j = 0; j < 4; ++j) acc[i][j] = zero4();

    for (int kk = 0; kk < 32; ++kk) {
        __syncthreads();
#pragma unroll
        for (int rr = 0; rr < 2; ++rr) {
            int r = srow + rr * 64;
            *(u16x8*)&As[r * 40 + sc16 * 8] =
                *(const u16x8*)(A + (size_t)(m0 + r) * 1024 + kk * 32 + sc16 * 8);
            *(u16x8*)&Bs[r * 40 + sc16 * 8] =
                *(const u16x8*)(Bt + (size_t)(n0 + r) * 1024 + kk * 32 + sc16 * 8);
        }
        __syncthreads();
        bf16x8 af[4], bf[4];
#pragma unroll
        for (int i = 0; i < 4; ++i) af[i] = *(const bf16x8*)&As[(wr * 64 + i * 16 + lm) * 40 + lq * 8];
#pragma unroll
        for (int j = 0; j < 4; ++j) bf[j] = *(const bf16x8*)&Bs[(wc * 64 + j * 16 + lm) * 40 + lq * 8];
#pragma unroll
        for (int i = 0; i < 4; ++i)
#pragma unroll
            for (int j = 0; j < 4; ++j)
                acc[i][j] = __builtin_amdgcn_mfma_f32_16x16x32_bf16(af[i], bf[j], acc[i][j], 0, 0, 0);
    }

    // epilogue: C/D layout col=lane&15, row=(lane>>4)*4+reg  [verified m89/m91]
#pragma unroll
    for (int i = 0; i < 4; ++i)
#pragma unroll
        for (int j = 0; j < 4; ++j) {
            int n = n0 + wc * 64 + j * 16 + lm;
            float bn = bias[n];
#pragma unroll
            for (int r = 0; r < 4; ++r) {
                int m = m0 + wr * 64 + i * 16 + lq * 4 + r;
                float v = acc[i][j][r] + bn;
                if (mode == 0) {
                    int b = m >> 11, s = m & 2047, h = n >> 6, hd = n & 63;
                    ((unsigned short*)outp)[((size_t)((b * NHEAD + h) * SEQ + s) << 6) + hd] = f2bf(v);
                } else if (mode == 1) {
                    int b = m >> 11, s = m & 2047, h = n >> 6, hd = n & 63;
                    ((unsigned short*)outp)[(size_t)((b * NHEAD + h) * HDIM + hd) * SEQ + s] = f2bf(v);
                } else {
                    size_t idx = (size_t)m * EMBED + n;
                    ((float*)outp)[idx] = v + residual[idx];
                }
            }
        }
}

// ---------------- flash attention: 1 block per (b, h, 64 q-rows) ----------------
__global__ __launch_bounds__(256) void attn_kernel(const unsigned short* __restrict__ Qp,
                                                   const unsigned short* __restrict__ Kp,
                                                   const unsigned short* __restrict__ Vt,
                                                   unsigned short* __restrict__ att) {
    __shared__ unsigned short Qs[64 * 72];        // rows padded to 72 bf16 (144 B)
    __shared__ unsigned short Ks[64 * 72];
    __shared__ unsigned short Vs[64 * 72];        // Vt tile: [hd][k]
    __shared__ unsigned short Ps[4][16 * 72];     // per-wave P strip (C-layout -> A-layout round trip)
    const int t = threadIdx.x;
    const int b = blockIdx.z, h = blockIdx.y, q0 = blockIdx.x * 64;
    const int bh = b * NHEAD + h;
    const unsigned short* Qh = Qp + (size_t)bh * SEQ * HDIM;
    const unsigned short* Kh = Kp + (size_t)bh * SEQ * HDIM;
    const unsigned short* Vh = Vt + (size_t)bh * HDIM * SEQ;
    const int wave = t >> 6, lane = t & 63, lm = lane & 15, lq = lane >> 4;
    const int srow = t >> 3, sc = t & 7;          // staging: 8 threads/row (128 B rows)

    // stage Q tile once (8 KB contiguous)
#pragma unroll
    for (int rr = 0; rr < 2; ++rr) {
        int r = srow + rr * 32;
        *(u16x8*)&Qs[r * 72 + sc * 8] = *(const u16x8*)(Qh + (size_t)(q0 + r) * HDIM + sc * 8);
    }
    __syncthreads();
    bf16x8 aq[2];
    aq[0] = *(const bf16x8*)&Qs[(wave * 16 + lm) * 72 + lq * 8];
    aq[1] = *(const bf16x8*)&Qs[(wave * 16 + lm) * 72 + 32 + lq * 8];

    f32x4 Oacc[4];
#pragma unroll
    for (int j = 0; j < 4; ++j) Oacc[j] = zero4();
    float mrow[4] = {-3e38f, -3e38f, -3e38f, -3e38f};
    float lrow[4] = {0.f, 0.f, 0.f, 0.f};

    for (int kt = 0; kt < 32; ++kt) {
        const int k0 = kt * 64;
        __syncthreads();    // protect previous iter's K/V reads
#pragma unroll
        for (int rr = 0; rr < 2; ++rr) {
            int r = srow + rr * 32;
            *(u16x8*)&Ks[r * 72 + sc * 8] = *(const u16x8*)(Kh + (size_t)(k0 + r) * HDIM + sc * 8);
            *(u16x8*)&Vs[r * 72 + sc * 8] = *(const u16x8*)(Vh + (size_t)r * SEQ + k0 + sc * 8);
        }
        __syncthreads();

        // S strip [16 q x 64 k] = Q . K^T
        f32x4 sacc[4];
#pragma unroll
        for (int j = 0; j < 4; ++j) sacc[j] = zero4();
#pragma unroll
        for (int j = 0; j < 4; ++j)
#pragma unroll
            for (int s = 0; s < 2; ++s) {
                bf16x8 bk = *(const bf16x8*)&Ks[(j * 16 + lm) * 72 + s * 32 + lq * 8];
                sacc[j] = __builtin_amdgcn_mfma_f32_16x16x32_bf16(aq[s], bk, sacc[j], 0, 0, 0);
            }

        // online softmax over k (row state replicated across the 16 lanes of each quad)
        const float sc_ = 0.125f;  // 1/sqrt(64)
        float alpha[4], p[4][4], rsum[4];
#pragma unroll
        for (int r = 0; r < 4; ++r) {
            float v = fmaxf(fmaxf(sacc[0][r], sacc[1][r]), fmaxf(sacc[2][r], sacc[3][r]));
            v = fmaxf(v, __shfl_xor(v, 1));
            v = fmaxf(v, __shfl_xor(v, 2));
            v = fmaxf(v, __shfl_xor(v, 4));
            v = fmaxf(v, __shfl_xor(v, 8));
            v *= sc_;
            float mn = fmaxf(mrow[r], v);
            alpha[r] = __expf(mrow[r] - mn);
            mrow[r] = mn;
            rsum[r] = 0.f;
        }
#pragma unroll
        for (int j = 0; j < 4; ++j)
#pragma unroll
            for (int r = 0; r < 4; ++r) {
                p[j][r] = __expf(sacc[j][r] * sc_ - mrow[r]);
                rsum[r] += p[j][r];
            }
#pragma unroll
        for (int r = 0; r < 4; ++r) {
            float s = rsum[r];
            s += __shfl_xor(s, 1);
            s += __shfl_xor(s, 2);
            s += __shfl_xor(s, 4);
            s += __shfl_xor(s, 8);
            lrow[r] = lrow[r] * alpha[r] + s;
        }
        // P: C-layout regs -> per-wave LDS strip (same-wave DS ops are in-order; no barrier)
#pragma unroll
        for (int j = 0; j < 4; ++j)
#pragma unroll
            for (int r = 0; r < 4; ++r)
                Ps[wave][(lq * 4 + r) * 72 + j * 16 + lm] = f2bf(p[j][r]);
        // rescale O
#pragma unroll
        for (int j = 0; j < 4; ++j)
#pragma unroll
            for (int r = 0; r < 4; ++r) Oacc[j][r] *= alpha[r];
        // O += P . V   (Vs holds V^T tile [hd][k], used as Bt)
#pragma unroll
        for (int s = 0; s < 2; ++s) {
            bf16x8 ap = *(const bf16x8*)&Ps[wave][lm * 72 + s * 32 + lq * 8];
#pragma unroll
            for (int j = 0; j < 4; ++j) {
                bf16x8 bv = *(const bf16x8*)&Vs[(j * 16 + lm) * 72 + s * 32 + lq * 8];
                Oacc[j] = __builtin_amdgcn_mfma_f32_16x16x32_bf16(ap, bv, Oacc[j], 0, 0, 0);
            }
        }
    }

    // normalize and write attended [b, q, h*64+hd] bf16
    float inv[4];
#pragma unroll
    for (int r = 0; r < 4; ++r) inv[r] = 1.f / lrow[r];
#pragma unroll
    for (int j = 0; j < 4; ++j)
#pragma unroll
        for (int r = 0; r < 4; ++r) {
            int qrow = q0 + wave * 16 + lq * 4 + r;
            int col = h * HDIM + j * 16 + lm;
            att[(size_t)(b * SEQ + qrow) * EMBED + col] = f2bf(Oacc[j][r] * inv[r]);
        }
}

// ---------------- row LayerNorm (one block per row) ----------------
__global__ __launch_bounds__(256) void ln_kernel(const float* __restrict__ x,
                                                 const float* __restrict__ gamma,
                                                 const float* __restrict__ beta,
                                                 float* __restrict__ out) {
    __shared__ float red[8];
    const int row = blockIdx.x, t = threadIdx.x;
    float4 v = *(const float4*)(x + (size_t)row * EMBED + t * 4);
    float s = v.x + v.y + v.z + v.w;
    float ss = v.x * v.x + v.y * v.y + v.z * v.z + v.w * v.w;
#pragma unroll
    for (int o = 1; o < 64; o <<= 1) {
        s += __shfl_xor(s, o);
        ss += __shfl_xor(ss, o);
    }
    int wave = t >> 6, lane = t & 63;
    if (lane == 0) { red[wave] = s; red[4 + wave] = ss; }
    __syncthreads();
    s = red[0] + red[1] + red[2] + red[3];
    ss = red[4] + red[5] + red[6] + red[7];
    float mu = s * (1.f / EMBED);
    float var = ss * (1.f / EMBED) - mu * mu;
    float rstd = rsqrtf(var + 1e-5f);
    float4 g = *(const float4*)(gamma + t * 4);
    float4 bb = *(const float4*)(beta + t * 4);
    float4 o;
    o.x = (v.x - mu) * rstd * g.x + bb.x;
    o.y = (v.y - mu) * rstd * g.y + bb.y;
    o.z = (v.z - mu) * rstd * g.z + bb.z;
    o.w = (v.w - mu) * rstd * g.w + bb.w;
    *(float4*)(out + (size_t)row * EMBED + t * 4) = o;
}

// ---------------- launch ----------------
extern "C" void kernel_launch(void* const* d_in, const int* in_sizes, int n_in,
                              void* d_out, int out_size, void* d_ws, size_t ws_size,
                              hipStream_t stream) {
    const float* query = (const float*)d_in[0];
    const float* key_  = (const float*)d_in[1];
    const float* value = (const float*)d_in[2];
    const float* Wq = (const float*)d_in[3];
    const float* bq = (const float*)d_in[4];
    const float* Wk = (const float*)d_in[5];
    const float* bk = (const float*)d_in[6];
    const float* Wv = (const float*)d_in[7];
    const float* bv = (const float*)d_in[8];
    const float* Wo = (const float*)d_in[9];
    const float* bo = (const float*)d_in[10];
    const float* gamma = (const float*)d_in[11];
    const float* beta  = (const float*)d_in[12];

    // workspace layout (56 MB total, with aliasing):
    //  [0,8)    qb   -> later att (qb dead after Q-proj)
    //  [8,24)   kb,vb -> later xbuf f32 (dead after K/V-proj)
    //  [24,32)  Wqt,Wkt,Wvt,Wot (2 MB each, bf16 [N,K])
    //  [32,40)  Qp  [B,H,S,HD] bf16
    //  [40,48)  Kp  [B,H,S,HD] bf16
    //  [48,56)  Vtb [B,H,HD,S] bf16
    char* ws = (char*)d_ws;
    const size_t MB = 1024 * 1024;
    unsigned short* qb  = (unsigned short*)(ws + 0);
    unsigned short* kb  = (unsigned short*)(ws + 8 * MB);
    unsigned short* vb  = (unsigned short*)(ws + 16 * MB);
    unsigned short* Wqt = (unsigned short*)(ws + 24 * MB);
    unsigned short* Wkt = (unsigned short*)(ws + 26 * MB);
    unsigned short* Wvt = (unsigned short*)(ws + 28 * MB);
    unsigned short* Wot = (unsigned short*)(ws + 30 * MB);
    unsigned short* Qp  = (unsigned short*)(ws + 32 * MB);
    unsigned short* Kp  = (unsigned short*)(ws + 40 * MB);
    unsigned short* Vtb = (unsigned short*)(ws + 48 * MB);
    unsigned short* att = (unsigned short*)(ws + 0);        // aliases qb
    float*          xbuf = (float*)(ws + 8 * MB);           // aliases kb+vb

    cvt_bf16_kernel<<<4096, 256, 0, stream>>>(query, qb);
    cvt_bf16_kernel<<<4096, 256, 0, stream>>>(key_, kb);
    cvt_bf16_kernel<<<4096, 256, 0, stream>>>(value, vb);
    dim3 tb(32, 8), tg(32, 32);
    transpose_cvt_kernel<<<tg, tb, 0, stream>>>(Wq, Wqt);
    transpose_cvt_kernel<<<tg, tb, 0, stream>>>(Wk, Wkt);
    transpose_cvt_kernel<<<tg, tb, 0, stream>>>(Wv, Wvt);
    transpose_cvt_kernel<<<tg, tb, 0, stream>>>(Wo, Wot);

    dim3 gg(8, 32);  // N/128, M/128
    gemm_bt_kernel<<<gg, 256, 0, stream>>>(qb, Wqt, bq, Qp, nullptr, 0);
    gemm_bt_kernel<<<gg, 256, 0, stream>>>(kb, Wkt, bk, Kp, nullptr, 0);
    gemm_bt_kernel<<<gg, 256, 0, stream>>>(vb, Wvt, bv, Vtb, nullptr, 1);

    attn_kernel<<<dim3(32, NHEAD, BATCH), 256, 0, stream>>>(Qp, Kp, Vtb, att);

    gemm_bt_kernel<<<gg, 256, 0, stream>>>(att, Wot, bo, xbuf, query, 2);
    ln_kernel<<<ROWS, 256, 0, stream>>>(xbuf, gamma, beta, (float*)d_out);
}

// Round 2
// 308.778 us; speedup vs baseline: 1.2686x; 1.2686x over previous
//
#include <hip/hip_runtime.h>

// ---------------- problem constants ----------------
#define EMBED 1024
#define NHEAD 16
#define HDIM  64
#define BATCH 2
#define SEQ   2048
#define ROWS  (BATCH*SEQ)   // 4096

typedef __bf16 bf16x8 __attribute__((ext_vector_type(8)));
typedef float  f32x4  __attribute__((ext_vector_type(4)));
typedef unsigned short u16x8 __attribute__((ext_vector_type(8)));
typedef unsigned short u16x4 __attribute__((ext_vector_type(4)));

__device__ __forceinline__ unsigned short f2bf(float f) {
    unsigned int u = __float_as_uint(f);
    u += 0x7FFFu + ((u >> 16) & 1u);          // round-to-nearest-even
    return (unsigned short)(u >> 16);
}
__device__ __forceinline__ f32x4 zero4() { f32x4 z = {0.f, 0.f, 0.f, 0.f}; return z; }

// async global->LDS, 16B per lane; lds dest must be wave-uniform base (+lane*16 by HW)
__device__ __forceinline__ void gl_lds16(const unsigned short* g, unsigned short* l) {
    __builtin_amdgcn_global_load_lds(
        (const __attribute__((address_space(1))) void*)g,
        (__attribute__((address_space(3))) void*)l, 16, 0, 0);
}

// ---------------- fused f32 -> bf16 cast for q/k/v (3 x 4M elements) ----------------
__global__ __launch_bounds__(256) void cvt3_kernel(const float* __restrict__ q,
                                                   const float* __restrict__ k,
                                                   const float* __restrict__ v,
                                                   unsigned short* __restrict__ qo,
                                                   unsigned short* __restrict__ ko,
                                                   unsigned short* __restrict__ vo) {
    const float* in; unsigned short* out;
    if (blockIdx.y == 0)      { in = q; out = qo; }
    else if (blockIdx.y == 1) { in = k; out = ko; }
    else                      { in = v; out = vo; }
    int i = (blockIdx.x * 256 + threadIdx.x) * 4;
    float4 vv = *(const float4*)(in + i);
    u16x4 o = {f2bf(vv.x), f2bf(vv.y), f2bf(vv.z), f2bf(vv.w)};
    *(u16x4*)(out + i) = o;
}

// ---------------- fused W [K,N] f32 -> Wt [N,K] bf16 for 4 weights ----------------
__global__ __launch_bounds__(256) void transpose4_kernel(const float* __restrict__ w0,
                                                         const float* __restrict__ w1,
                                                         const float* __restrict__ w2,
                                                         const float* __restrict__ w3,
                                                         unsigned short* __restrict__ o0,
                                                         unsigned short* __restrict__ o1,
                                                         unsigned short* __restrict__ o2,
                                                         unsigned short* __restrict__ o3) {
    const float* in; unsigned short* out;
    if (blockIdx.z == 0)      { in = w0; out = o0; }
    else if (blockIdx.z == 1) { in = w1; out = o1; }
    else if (blockIdx.z == 2) { in = w2; out = o2; }
    else                      { in = w3; out = o3; }
    __shared__ float tile[32][33];
    int tx = threadIdx.x, ty = threadIdx.y;              // 32 x 8
    int x = blockIdx.x * 32 + tx;
    int y0 = blockIdx.y * 32 + ty;
#pragma unroll
    for (int r = 0; r < 4; ++r)
        tile[ty + 8 * r][tx] = in[(size_t)(y0 + 8 * r) * EMBED + x];
    __syncthreads();
    int ox = blockIdx.y * 32 + tx;
    int oy = blockIdx.x * 32 + ty;
#pragma unroll
    for (int r = 0; r < 4; ++r)
        out[(size_t)(oy + 8 * r) * EMBED + ox] = f2bf(tile[tx][ty + 8 * r]);
}

// ---------------- m97-style bf16 GEMM core: C[M,128] tile = A[M,1024] * Bt[N,1024]^T ----------------
// LDS tiles 128x32 bf16, unpadded, chunk-XOR swizzle: 16B chunk c of row r stored at
// position c ^ ((r>>1)&3). Staged via global_load_lds (async, no VGPR round trip).
// mode 0: out bf16 [B,H,S,HD] scaled by oscale  (Q: oscale=0.125 pre-applies 1/sqrt(HD); K: 1.0)
// mode 1: out bf16 [B,H,HD,S]                   (V, pre-transposed for PV)
// mode 2: out f32  [M,N] = acc + bias + residual (O-projection)
__device__ __forceinline__ void gemm_core(const unsigned short* __restrict__ A,
                                          const unsigned short* __restrict__ Bt,
                                          const float* __restrict__ bias,
                                          void* __restrict__ outp,
                                          const float* __restrict__ residual,
                                          int mode, float oscale,
                                          unsigned short* As, unsigned short* Bs) {
    const int t = threadIdx.x;
    const int m0 = blockIdx.y * 128, n0 = blockIdx.x * 128;
    const int wave = t >> 6, lane = t & 63;
    const int wr = wave >> 1, wc = wave & 1;             // 2x2 wave grid, 64x64 each
    const int lm = lane & 15, lq = lane >> 4;
    const int sr = t >> 2;                               // staging row 0..63
    const int csrc = (t & 3) ^ ((sr >> 1) & 3);          // source chunk for stored position t&3
    const int pa = lq ^ ((lm >> 1) & 3);                 // fragment chunk position (rows are 16-aligned)

    const unsigned short* gA = A + (size_t)(m0 + sr) * EMBED + csrc * 8;
    const unsigned short* gB = Bt + (size_t)(n0 + sr) * EMBED + csrc * 8;
    unsigned short* lA0 = As + wave * 512;               // wave-uniform LDS bases
    unsigned short* lA1 = As + 2048 + wave * 512;
    unsigned short* lB0 = Bs + wave * 512;
    unsigned short* lB1 = Bs + 2048 + wave * 512;

    f32x4 acc[4][4];
#pragma unroll
    for (int i = 0; i < 4; ++i)
#pragma unroll
        for (int j = 0; j < 4; ++j) acc[i][j] = zero4();

    for (int kk = 0; kk < 32; ++kk) {
        __syncthreads();
        gl_lds16(gA, lA0);
        gl_lds16(gA + 64 * EMBED, lA1);
        gl_lds16(gB, lB0);
        gl_lds16(gB + 64 * EMBED, lB1);
        gA += 32; gB += 32;
        __syncthreads();
        bf16x8 af[4], bfr[4];
#pragma unroll
        for (int i = 0; i < 4; ++i)
            af[i] = *(const bf16x8*)&As[(wr * 64 + i * 16 + lm) * 32 + pa * 8];
#pragma unroll
        for (int j = 0; j < 4; ++j)
            bfr[j] = *(const bf16x8*)&Bs[(wc * 64 + j * 16 + lm) * 32 + pa * 8];
#pragma unroll
        for (int i = 0; i < 4; ++i)
#pragma unroll
            for (int j = 0; j < 4; ++j)
                acc[i][j] = __builtin_amdgcn_mfma_f32_16x16x32_bf16(af[i], bfr[j], acc[i][j], 0, 0, 0);
    }

    // epilogue: C/D layout col=lane&15, row=(lane>>4)*4+reg  [verified m89/m91]
#pragma unroll
    for (int i = 0; i < 4; ++i)
#pragma unroll
        for (int j = 0; j < 4; ++j) {
            int n = n0 + wc * 64 + j * 16 + lm;
            float bn = bias[n];
#pragma unroll
            for (int r = 0; r < 4; ++r) {
                int m = m0 + wr * 64 + i * 16 + lq * 4 + r;
                float v = acc[i][j][r] + bn;
                if (mode == 0) {
                    int b = m >> 11, s = m & 2047, h = n >> 6, hd = n & 63;
                    ((unsigned short*)outp)[((size_t)((b * NHEAD + h) * SEQ + s) << 6) + hd] = f2bf(v * oscale);
                } else if (mode == 1) {
                    int b = m >> 11, s = m & 2047, h = n >> 6, hd = n & 63;
                    ((unsigned short*)outp)[(size_t)((b * NHEAD + h) * HDIM + hd) * SEQ + s] = f2bf(v);
                } else {
                    size_t idx = (size_t)m * EMBED + n;
                    ((float*)outp)[idx] = v + residual[idx];
                }
            }
        }
}

// fused Q/K/V projection: blockIdx.z selects the problem (768 blocks total = 3/CU)
__global__ __launch_bounds__(256, 2) void gemm_qkv_kernel(
    const unsigned short* __restrict__ qb, const unsigned short* __restrict__ kb,
    const unsigned short* __restrict__ vb,
    const unsigned short* __restrict__ Wqt, const unsigned short* __restrict__ Wkt,
    const unsigned short* __restrict__ Wvt,
    const float* __restrict__ bq, const float* __restrict__ bk, const float* __restrict__ bv,
    unsigned short* __restrict__ Qp, unsigned short* __restrict__ Kp,
    unsigned short* __restrict__ Vtb) {
    __shared__ unsigned short As[128 * 32];
    __shared__ unsigned short Bs[128 * 32];
    const unsigned short *A, *Bt; const float* bias; void* outp; int mode; float osc;
    if (blockIdx.z == 0)      { A = qb; Bt = Wqt; bias = bq; outp = Qp;  mode = 0; osc = 0.125f; }
    else if (blockIdx.z == 1) { A = kb; Bt = Wkt; bias = bk; outp = Kp;  mode = 0; osc = 1.0f; }
    else                      { A = vb; Bt = Wvt; bias = bv; outp = Vtb; mode = 1; osc = 1.0f; }
    gemm_core(A, Bt, bias, outp, nullptr, mode, osc, As, Bs);
}

__global__ __launch_bounds__(256, 2) void gemm_o_kernel(
    const unsigned short* __restrict__ att, const unsigned short* __restrict__ Wot,
    const float* __restrict__ bo, float* __restrict__ xbuf,
    const float* __restrict__ residual) {
    __shared__ unsigned short As[128 * 32];
    __shared__ unsigned short Bs[128 * 32];
    gemm_core(att, Wot, bo, (void*)xbuf, residual, 2, 1.0f, As, Bs);
}

// ---------------- flash attention: 1 block per (b, h, 64 q-rows), reg-prefetch dbuf ----------------
__global__ __launch_bounds__(256) void attn_kernel(const unsigned short* __restrict__ Qp,
                                                   const unsigned short* __restrict__ Kp,
                                                   const unsigned short* __restrict__ Vt,
                                                   unsigned short* __restrict__ att) {
    __shared__ unsigned short Qs[64 * 72];        // rows padded to 72 bf16 (144 B, 2-way banks)
    __shared__ unsigned short Ks[64 * 72];
    __shared__ unsigned short Vs[64 * 72];        // Vt tile: [hd][k]
    __shared__ unsigned short Ps[4][16 * 72];     // per-wave P strip (C-layout -> A-layout)
    const int t = threadIdx.x;
    const int b = blockIdx.z, h = blockIdx.y, q0 = blockIdx.x * 64;
    const int bh = b * NHEAD + h;
    const unsigned short* Qh = Qp + (size_t)bh * SEQ * HDIM;
    const unsigned short* Kh = Kp + (size_t)bh * SEQ * HDIM;
    const unsigned short* Vh = Vt + (size_t)bh * HDIM * SEQ;
    const int wave = t >> 6, lane = t & 63, lm = lane & 15, lq = lane >> 4;
    const int srow = t >> 3, sc = t & 7;          // staging: 8 threads/row (128 B rows)

    // stage Q tile once (Q is pre-scaled by 1/sqrt(HD) in its projection epilogue)
#pragma unroll
    for (int rr = 0; rr < 2; ++rr) {
        int r = srow + rr * 32;
        *(u16x8*)&Qs[r * 72 + sc * 8] = *(const u16x8*)(Qh + (size_t)(q0 + r) * HDIM + sc * 8);
    }
    __syncthreads();
    bf16x8 aq[2];
    aq[0] = *(const bf16x8*)&Qs[(wave * 16 + lm) * 72 + lq * 8];
    aq[1] = *(const bf16x8*)&Qs[(wave * 16 + lm) * 72 + 32 + lq * 8];

    // prefetch K/V tile 0 into registers
    u16x8 kr0, kr1, vr0, vr1;
    kr0 = *(const u16x8*)(Kh + (size_t)srow * HDIM + sc * 8);
    kr1 = *(const u16x8*)(Kh + (size_t)(srow + 32) * HDIM + sc * 8);
    vr0 = *(const u16x8*)(Vh + (size_t)srow * SEQ + sc * 8);
    vr1 = *(const u16x8*)(Vh + (size_t)(srow + 32) * SEQ + sc * 8);

    f32x4 Oacc[4];
#pragma unroll
    for (int j = 0; j < 4; ++j) Oacc[j] = zero4();
    float mrow[4] = {-3e38f, -3e38f, -3e38f, -3e38f};
    float lrow[4] = {0.f, 0.f, 0.f, 0.f};

    for (int kt = 0; kt < 32; ++kt) {
        __syncthreads();                          // prev iter's LDS reads done
        *(u16x8*)&Ks[srow * 72 + sc * 8] = kr0;
        *(u16x8*)&Ks[(srow + 32) * 72 + sc * 8] = kr1;
        *(u16x8*)&Vs[srow * 72 + sc * 8] = vr0;
        *(u16x8*)&Vs[(srow + 32) * 72 + sc * 8] = vr1;
        __syncthreads();                          // tile visible
        if (kt < 31) {                            // prefetch next tile; latency hidden by compute
            int k0n = (kt + 1) * 64;
            kr0 = *(const u16x8*)(Kh + (size_t)(k0n + srow) * HDIM + sc * 8);
            kr1 = *(const u16x8*)(Kh + (size_t)(k0n + srow + 32) * HDIM + sc * 8);
            vr0 = *(const u16x8*)(Vh + (size_t)srow * SEQ + k0n + sc * 8);
            vr1 = *(const u16x8*)(Vh + (size_t)(srow + 32) * SEQ + k0n + sc * 8);
        }

        // S strip [16 q x 64 k] = Q . K^T   (already includes 1/sqrt(HD) via Q pre-scale)
        f32x4 sacc[4];
#pragma unroll
        for (int j = 0; j < 4; ++j) sacc[j] = zero4();
#pragma unroll
        for (int j = 0; j < 4; ++j)
#pragma unroll
            for (int s = 0; s < 2; ++s) {
                bf16x8 bk = *(const bf16x8*)&Ks[(j * 16 + lm) * 72 + s * 32 + lq * 8];
                sacc[j] = __builtin_amdgcn_mfma_f32_16x16x32_bf16(aq[s], bk, sacc[j], 0, 0, 0);
            }

        // online softmax over k (row state replicated across the 16 lanes of each quad)
        float alpha[4], p[4][4], rsum[4];
#pragma unroll
        for (int r = 0; r < 4; ++r) {
            float v = fmaxf(fmaxf(sacc[0][r], sacc[1][r]), fmaxf(sacc[2][r], sacc[3][r]));
            v = fmaxf(v, __shfl_xor(v, 1));
            v = fmaxf(v, __shfl_xor(v, 2));
            v = fmaxf(v, __shfl_xor(v, 4));
            v = fmaxf(v, __shfl_xor(v, 8));
            float mn = fmaxf(mrow[r], v);
            alpha[r] = __expf(mrow[r] - mn);
            mrow[r] = mn;
            rsum[r] = 0.f;
        }
#pragma unroll
        for (int j = 0; j < 4; ++j)
#pragma unroll
            for (int r = 0; r < 4; ++r) {
                p[j][r] = __expf(sacc[j][r] - mrow[r]);
                rsum[r] += p[j][r];
            }
#pragma unroll
        for (int r = 0; r < 4; ++r) {
            float s = rsum[r];
            s += __shfl_xor(s, 1);
            s += __shfl_xor(s, 2);
            s += __shfl_xor(s, 4);
            s += __shfl_xor(s, 8);
            lrow[r] = lrow[r] * alpha[r] + s;
        }
        // P: C-layout regs -> per-wave LDS strip (same-wave DS ops in-order; no barrier)
#pragma unroll
        for (int j = 0; j < 4; ++j)
#pragma unroll
            for (int r = 0; r < 4; ++r)
                Ps[wave][(lq * 4 + r) * 72 + j * 16 + lm] = f2bf(p[j][r]);
        // rescale O
#pragma unroll
        for (int j = 0; j < 4; ++j)
#pragma unroll
            for (int r = 0; r < 4; ++r) Oacc[j][r] *= alpha[r];
        // O += P . V   (Vs holds V^T tile [hd][k], used as Bt)
#pragma unroll
        for (int s = 0; s < 2; ++s) {
            bf16x8 ap = *(const bf16x8*)&Ps[wave][lm * 72 + s * 32 + lq * 8];
#pragma unroll
            for (int j = 0; j < 4; ++j) {
                bf16x8 bv = *(const bf16x8*)&Vs[(j * 16 + lm) * 72 + s * 32 + lq * 8];
                Oacc[j] = __builtin_amdgcn_mfma_f32_16x16x32_bf16(ap, bv, Oacc[j], 0, 0, 0);
            }
        }
    }

    // normalize and write attended [b, q, h*64+hd] bf16
    float inv[4];
#pragma unroll
    for (int r = 0; r < 4; ++r) inv[r] = 1.f / lrow[r];
#pragma unroll
    for (int j = 0; j < 4; ++j)
#pragma unroll
        for (int r = 0; r < 4; ++r) {
            int qrow = q0 + wave * 16 + lq * 4 + r;
            int col = h * HDIM + j * 16 + lm;
            att[(size_t)(b * SEQ + qrow) * EMBED + col] = f2bf(Oacc[j][r] * inv[r]);
        }
}

// ---------------- row LayerNorm (one block per row) ----------------
__global__ __launch_bounds__(256) void ln_kernel(const float* __restrict__ x,
                                                 const float* __restrict__ gamma,
                                                 const float* __restrict__ beta,
                                                 float* __restrict__ out) {
    __shared__ float red[8];
    const int row = blockIdx.x, t = threadIdx.x;
    float4 v = *(const float4*)(x + (size_t)row * EMBED + t * 4);
    float s = v.x + v.y + v.z + v.w;
    float ss = v.x * v.x + v.y * v.y + v.z * v.z + v.w * v.w;
#pragma unroll
    for (int o = 1; o < 64; o <<= 1) {
        s += __shfl_xor(s, o);
        ss += __shfl_xor(ss, o);
    }
    int wave = t >> 6, lane = t & 63;
    if (lane == 0) { red[wave] = s; red[4 + wave] = ss; }
    __syncthreads();
    s = red[0] + red[1] + red[2] + red[3];
    ss = red[4] + red[5] + red[6] + red[7];
    float mu = s * (1.f / EMBED);
    float var = ss * (1.f / EMBED) - mu * mu;
    float rstd = rsqrtf(var + 1e-5f);
    float4 g = *(const float4*)(gamma + t * 4);
    float4 bb = *(const float4*)(beta + t * 4);
    float4 o;
    o.x = (v.x - mu) * rstd * g.x + bb.x;
    o.y = (v.y - mu) * rstd * g.y + bb.y;
    o.z = (v.z - mu) * rstd * g.z + bb.z;
    o.w = (v.w - mu) * rstd * g.w + bb.w;
    *(float4*)(out + (size_t)row * EMBED + t * 4) = o;
}

// ---------------- launch ----------------
extern "C" void kernel_launch(void* const* d_in, const int* in_sizes, int n_in,
                              void* d_out, int out_size, void* d_ws, size_t ws_size,
                              hipStream_t stream) {
    const float* query = (const float*)d_in[0];
    const float* key_  = (const float*)d_in[1];
    const float* value = (const float*)d_in[2];
    const float* Wq = (const float*)d_in[3];
    const float* bq = (const float*)d_in[4];
    const float* Wk = (const float*)d_in[5];
    const float* bk = (const float*)d_in[6];
    const float* Wv = (const float*)d_in[7];
    const float* bv = (const float*)d_in[8];
    const float* Wo = (const float*)d_in[9];
    const float* bo = (const float*)d_in[10];
    const float* gamma = (const float*)d_in[11];
    const float* beta  = (const float*)d_in[12];

    char* ws = (char*)d_ws;
    const size_t MB = 1024 * 1024;
    unsigned short* qb  = (unsigned short*)(ws + 0);
    unsigned short* kb  = (unsigned short*)(ws + 8 * MB);
    unsigned short* vb  = (unsigned short*)(ws + 16 * MB);
    unsigned short* Wqt = (unsigned short*)(ws + 24 * MB);
    unsigned short* Wkt = (unsigned short*)(ws + 26 * MB);
    unsigned short* Wvt = (unsigned short*)(ws + 28 * MB);
    unsigned short* Wot = (unsigned short*)(ws + 30 * MB);
    unsigned short* Qp  = (unsigned short*)(ws + 32 * MB);
    unsigned short* Kp  = (unsigned short*)(ws + 40 * MB);
    unsigned short* Vtb = (unsigned short*)(ws + 48 * MB);
    unsigned short* att = (unsigned short*)(ws + 0);        // aliases qb (dead after Q-proj)
    float*          xbuf = (float*)(ws + 8 * MB);           // aliases kb+vb (dead after K/V-proj)

    cvt3_kernel<<<dim3(4096, 3), 256, 0, stream>>>(query, key_, value, qb, kb, vb);
    transpose4_kernel<<<dim3(32, 32, 4), dim3(32, 8), 0, stream>>>(Wq, Wk, Wv, Wo, Wqt, Wkt, Wvt, Wot);

    gemm_qkv_kernel<<<dim3(8, 32, 3), 256, 0, stream>>>(qb, kb, vb, Wqt, Wkt, Wvt,
                                                        bq, bk, bv, Qp, Kp, Vtb);

    attn_kernel<<<dim3(32, NHEAD, BATCH), 256, 0, stream>>>(Qp, Kp, Vtb, att);

    gemm_o_kernel<<<dim3(8, 32), 256, 0, stream>>>(att, Wot, bo, xbuf, query);
    ln_kernel<<<ROWS, 256, 0, stream>>>(xbuf, gamma, beta, (float*)d_out);
}

// Round 3
// 254.800 us; speedup vs baseline: 1.5374x; 1.2118x over previous
//
#include <hip/hip_runtime.h>

// ---------------- problem constants ----------------
#define EMBED 1024
#define NHEAD 16
#define HDIM  64
#define BATCH 2
#define SEQ   2048
#define ROWS  (BATCH*SEQ)   // 4096

typedef __bf16 bf16x8 __attribute__((ext_vector_type(8)));
typedef float  f32x4  __attribute__((ext_vector_type(4)));
typedef float  f32x16 __attribute__((ext_vector_type(16)));
typedef unsigned short u16x8 __attribute__((ext_vector_type(8)));
typedef unsigned short u16x4 __attribute__((ext_vector_type(4)));

__device__ __forceinline__ unsigned short f2bf(float f) {
    unsigned int u = __float_as_uint(f);
    u += 0x7FFFu + ((u >> 16) & 1u);          // round-to-nearest-even
    return (unsigned short)(u >> 16);
}
__device__ __forceinline__ f32x4 zero4() { f32x4 z = {0.f, 0.f, 0.f, 0.f}; return z; }

// async global->LDS, 16B per lane; lds dest is wave-uniform base (+lane*16 by HW)
__device__ __forceinline__ void gl_lds16(const unsigned short* g, unsigned short* l) {
    __builtin_amdgcn_global_load_lds(
        (const __attribute__((address_space(1))) void*)g,
        (__attribute__((address_space(3))) void*)l, 16, 0, 0);
}

// ---------------- fused f32 -> bf16 cast for q/k/v ----------------
__global__ __launch_bounds__(256) void cvt3_kernel(const float* __restrict__ q,
                                                   const float* __restrict__ k,
                                                   const float* __restrict__ v,
                                                   unsigned short* __restrict__ qo,
                                                   unsigned short* __restrict__ ko,
                                                   unsigned short* __restrict__ vo) {
    const float* in; unsigned short* out;
    if (blockIdx.y == 0)      { in = q; out = qo; }
    else if (blockIdx.y == 1) { in = k; out = ko; }
    else                      { in = v; out = vo; }
    int i = (blockIdx.x * 256 + threadIdx.x) * 4;
    float4 vv = *(const float4*)(in + i);
    u16x4 o = {f2bf(vv.x), f2bf(vv.y), f2bf(vv.z), f2bf(vv.w)};
    *(u16x4*)(out + i) = o;
}

// ---------------- fused W [K,N] f32 -> Wt [N,K] bf16 for 4 weights ----------------
__global__ __launch_bounds__(256) void transpose4_kernel(const float* __restrict__ w0,
                                                         const float* __restrict__ w1,
                                                         const float* __restrict__ w2,
                                                         const float* __restrict__ w3,
                                                         unsigned short* __restrict__ o0,
                                                         unsigned short* __restrict__ o1,
                                                         unsigned short* __restrict__ o2,
                                                         unsigned short* __restrict__ o3) {
    const float* in; unsigned short* out;
    if (blockIdx.z == 0)      { in = w0; out = o0; }
    else if (blockIdx.z == 1) { in = w1; out = o1; }
    else if (blockIdx.z == 2) { in = w2; out = o2; }
    else                      { in = w3; out = o3; }
    __shared__ float tile[32][33];
    int tx = threadIdx.x, ty = threadIdx.y;              // 32 x 8
    int x = blockIdx.x * 32 + tx;
    int y0 = blockIdx.y * 32 + ty;
#pragma unroll
    for (int r = 0; r < 4; ++r)
        tile[ty + 8 * r][tx] = in[(size_t)(y0 + 8 * r) * EMBED + x];
    __syncthreads();
    int ox = blockIdx.y * 32 + tx;
    int oy = blockIdx.x * 32 + ty;
#pragma unroll
    for (int r = 0; r < 4; ++r)
        out[(size_t)(oy + 8 * r) * EMBED + ox] = f2bf(tile[tx][ty + 8 * r]);
}

// ---------------- 128x128 bf16 GEMM core (qkv projections) ----------------
// mode 0: out bf16 [B,H,S,HD] scaled by oscale  (Q: 0.125 folds in 1/sqrt(HD); K: 1.0)
// mode 1: out bf16 [B,H,HD,S]                   (V, pre-transposed for PV)
__device__ __forceinline__ void gemm_core(const unsigned short* __restrict__ A,
                                          const unsigned short* __restrict__ Bt,
                                          const float* __restrict__ bias,
                                          void* __restrict__ outp,
                                          int mode, float oscale,
                                          unsigned short* As, unsigned short* Bs) {
    const int t = threadIdx.x;
    const int m0 = blockIdx.y * 128, n0 = blockIdx.x * 128;
    const int wave = t >> 6, lane = t & 63;
    const int wr = wave >> 1, wc = wave & 1;             // 2x2 wave grid, 64x64 each
    const int lm = lane & 15, lq = lane >> 4;
    const int sr = t >> 2;                               // staging row 0..63
    const int csrc = (t & 3) ^ ((sr >> 1) & 3);          // source chunk for stored position t&3
    const int pa = lq ^ ((lm >> 1) & 3);                 // fragment chunk position

    const unsigned short* gA = A + (size_t)(m0 + sr) * EMBED + csrc * 8;
    const unsigned short* gB = Bt + (size_t)(n0 + sr) * EMBED + csrc * 8;
    unsigned short* lA0 = As + wave * 512;
    unsigned short* lA1 = As + 2048 + wave * 512;
    unsigned short* lB0 = Bs + wave * 512;
    unsigned short* lB1 = Bs + 2048 + wave * 512;

    f32x4 acc[4][4];
#pragma unroll
    for (int i = 0; i < 4; ++i)
#pragma unroll
        for (int j = 0; j < 4; ++j) acc[i][j] = zero4();

    for (int kk = 0; kk < 32; ++kk) {
        __syncthreads();
        gl_lds16(gA, lA0);
        gl_lds16(gA + 64 * EMBED, lA1);
        gl_lds16(gB, lB0);
        gl_lds16(gB + 64 * EMBED, lB1);
        gA += 32; gB += 32;
        __syncthreads();
        bf16x8 af[4], bfr[4];
#pragma unroll
        for (int i = 0; i < 4; ++i)
            af[i] = *(const bf16x8*)&As[(wr * 64 + i * 16 + lm) * 32 + pa * 8];
#pragma unroll
        for (int j = 0; j < 4; ++j)
            bfr[j] = *(const bf16x8*)&Bs[(wc * 64 + j * 16 + lm) * 32 + pa * 8];
#pragma unroll
        for (int i = 0; i < 4; ++i)
#pragma unroll
            for (int j = 0; j < 4; ++j)
                acc[i][j] = __builtin_amdgcn_mfma_f32_16x16x32_bf16(af[i], bfr[j], acc[i][j], 0, 0, 0);
    }

#pragma unroll
    for (int i = 0; i < 4; ++i)
#pragma unroll
        for (int j = 0; j < 4; ++j) {
            int n = n0 + wc * 64 + j * 16 + lm;
            float bn = bias[n];
#pragma unroll
            for (int r = 0; r < 4; ++r) {
                int m = m0 + wr * 64 + i * 16 + lq * 4 + r;
                float v = acc[i][j][r] + bn;
                int b = m >> 11, s = m & 2047, h = n >> 6, hd = n & 63;
                if (mode == 0)
                    ((unsigned short*)outp)[((size_t)((b * NHEAD + h) * SEQ + s) << 6) + hd] = f2bf(v * oscale);
                else
                    ((unsigned short*)outp)[(size_t)((b * NHEAD + h) * HDIM + hd) * SEQ + s] = f2bf(v);
            }
        }
}

__global__ __launch_bounds__(256, 2) void gemm_qkv_kernel(
    const unsigned short* __restrict__ qb, const unsigned short* __restrict__ kb,
    const unsigned short* __restrict__ vb,
    const unsigned short* __restrict__ Wqt, const unsigned short* __restrict__ Wkt,
    const unsigned short* __restrict__ Wvt,
    const float* __restrict__ bq, const float* __restrict__ bk, const float* __restrict__ bv,
    unsigned short* __restrict__ Qp, unsigned short* __restrict__ Kp,
    unsigned short* __restrict__ Vtb) {
    __shared__ unsigned short As[128 * 32];
    __shared__ unsigned short Bs[128 * 32];
    const unsigned short *A, *Bt; const float* bias; void* outp; int mode; float osc;
    if (blockIdx.z == 0)      { A = qb; Bt = Wqt; bias = bq; outp = Qp;  mode = 0; osc = 0.125f; }
    else if (blockIdx.z == 1) { A = kb; Bt = Wkt; bias = bk; outp = Kp;  mode = 0; osc = 1.0f; }
    else                      { A = vb; Bt = Wvt; bias = bv; outp = Vtb; mode = 1; osc = 1.0f; }
    gemm_core(A, Bt, bias, outp, mode, osc, As, Bs);
}

// ---------------- O-projection GEMM: M64 x N128 tiles -> 512 blocks = 2/CU ----------------
__global__ __launch_bounds__(256, 2) void gemm_o_kernel(
    const unsigned short* __restrict__ att, const unsigned short* __restrict__ Wot,
    const float* __restrict__ bo, float* __restrict__ xbuf,
    const float* __restrict__ residual) {
    __shared__ unsigned short As[64 * 32];    // 4 KB
    __shared__ unsigned short Bs[128 * 32];   // 8 KB
    const int t = threadIdx.x;
    const int m0 = blockIdx.y * 64, n0 = blockIdx.x * 128;
    const int wave = t >> 6, lane = t & 63;
    const int lm = lane & 15, lq = lane >> 4;
    const int sr = t >> 2;
    const int csrc = (t & 3) ^ ((sr >> 1) & 3);
    const int pa = lq ^ ((lm >> 1) & 3);

    const unsigned short* gA = att + (size_t)(m0 + sr) * EMBED + csrc * 8;
    const unsigned short* gB = Wot + (size_t)(n0 + sr) * EMBED + csrc * 8;
    unsigned short* lA  = As + wave * 512;
    unsigned short* lB0 = Bs + wave * 512;
    unsigned short* lB1 = Bs + 2048 + wave * 512;

    f32x4 acc[4][2];
#pragma unroll
    for (int i = 0; i < 4; ++i)
#pragma unroll
        for (int j = 0; j < 2; ++j) acc[i][j] = zero4();

    for (int kk = 0; kk < 32; ++kk) {
        __syncthreads();
        gl_lds16(gA, lA);
        gl_lds16(gB, lB0);
        gl_lds16(gB + 64 * EMBED, lB1);
        gA += 32; gB += 32;
        __syncthreads();
        bf16x8 af[4], bfr[2];
#pragma unroll
        for (int i = 0; i < 4; ++i)
            af[i] = *(const bf16x8*)&As[(i * 16 + lm) * 32 + pa * 8];
#pragma unroll
        for (int j = 0; j < 2; ++j)
            bfr[j] = *(const bf16x8*)&Bs[(wave * 32 + j * 16 + lm) * 32 + pa * 8];
#pragma unroll
        for (int i = 0; i < 4; ++i)
#pragma unroll
            for (int j = 0; j < 2; ++j)
                acc[i][j] = __builtin_amdgcn_mfma_f32_16x16x32_bf16(af[i], bfr[j], acc[i][j], 0, 0, 0);
    }

#pragma unroll
    for (int i = 0; i < 4; ++i)
#pragma unroll
        for (int j = 0; j < 2; ++j) {
            int n = n0 + wave * 32 + j * 16 + lm;
            float bn = bo[n];
#pragma unroll
            for (int r = 0; r < 4; ++r) {
                int m = m0 + i * 16 + lq * 4 + r;
                size_t idx = (size_t)m * EMBED + n;
                xbuf[idx] = acc[i][j][r] + bn + residual[idx];
            }
        }
}

// ---------------- flash attention: S^T scheme, 32x32x16 MFMA, frag-contiguous LDS ----------------
// Block = 128 q rows (4 waves x 32 q), k-tile = 64. Grid (32 bh, 16 q-tiles) = 512 = 2/CU.
// S^T = K.Q^T puts softmax per-lane (q = lane&31): in-lane tree + one shfl_xor(32).
// LDS layouts are fragment-contiguous: frag f (1KB) at f*512 bf16, element (m, k=hf*8+j)
// at f*512 + hf*256 + m*8 + j  ->  every b128 frag read is a 64-lane contiguous 1KB access.
__global__ __launch_bounds__(256, 2) void attn_kernel(const unsigned short* __restrict__ Qp,
                                                      const unsigned short* __restrict__ Kp,
                                                      const unsigned short* __restrict__ Vt,
                                                      unsigned short* __restrict__ att) {
    __shared__ unsigned short Ks[4096];   // 8 frags: f = mt*4+s  (mt = k'>>5, s = hd>>4)
    __shared__ unsigned short Vs[4096];   // 8 frags: f = mt'*4+s' (mt' = hd>>5, s' = k'>>4)
    __shared__ unsigned short Ps[8192];   // 4 waves x 4 frags (s' = k'>>4), B-operand layout
    const int t = threadIdx.x;
    const int bh = blockIdx.x;            // bh on x: all q-tiles of a head land on one XCD
    const int b = bh >> 4, h = bh & 15;
    const int q0 = blockIdx.y * 128;
    const unsigned short* Qh = Qp + (size_t)bh * SEQ * HDIM;
    const unsigned short* Kh = Kp + (size_t)bh * SEQ * HDIM;
    const unsigned short* Vh = Vt + (size_t)bh * HDIM * SEQ;
    const int wave = t >> 6, lane = t & 63;
    const int ln31 = lane & 31, half = lane >> 5;

    // Q B-frags held in regs: B[n=q=ln31][k = s*16 + half*8 + j]  (Q pre-scaled by 1/8)
    bf16x8 qf[4];
    {
        const unsigned short* qptr = Qh + (size_t)(q0 + wave * 32 + ln31) * HDIM + half * 8;
#pragma unroll
        for (int s = 0; s < 4; ++s) qf[s] = *(const bf16x8*)(qptr + s * 16);
    }

    // staging: thread t owns chunk ids q8a = t, q8b = 256+t (8 bf16 each); LDS addr = q8*8.
    const int q8a = t, q8b = 256 + t;
    // K chunk q8 -> global elem: row = (f>>2)*32 + (q8&31), col = (f&3)*16 + ((q8>>5)&1)*8
    const int fa = q8a >> 6, fb = q8b >> 6;
    const int ma = q8a & 31, mb = q8b & 31;
    const int ha = (q8a >> 5) & 1, hb = (q8b >> 5) & 1;
    const unsigned short* gK0 = Kh + (size_t)((fa >> 2) * 32 + ma) * HDIM + (fa & 3) * 16 + ha * 8;
    const unsigned short* gK1 = Kh + (size_t)((fb >> 2) * 32 + mb) * HDIM + (fb & 3) * 16 + hb * 8;
    const unsigned short* gV0 = Vh + (size_t)((fa >> 2) * 32 + ma) * SEQ + (fa & 3) * 16 + ha * 8;
    const unsigned short* gV1 = Vh + (size_t)((fb >> 2) * 32 + mb) * SEQ + (fb & 3) * 16 + hb * 8;
    u16x8 kr0 = *(const u16x8*)gK0, kr1 = *(const u16x8*)gK1;
    u16x8 vr0 = *(const u16x8*)gV0, vr1 = *(const u16x8*)gV1;

    f32x16 Oacc[2];
#pragma unroll
    for (int mt = 0; mt < 2; ++mt)
#pragma unroll
        for (int r = 0; r < 16; ++r) Oacc[mt][r] = 0.f;
    float m_run = -3e38f, l_run = 0.f;

    unsigned short* PsW = Ps + wave * 2048;

    for (int kt = 0; kt < 32; ++kt) {
        __syncthreads();
        *(u16x8*)&Ks[q8a * 8] = kr0;  *(u16x8*)&Ks[q8b * 8] = kr1;
        *(u16x8*)&Vs[q8a * 8] = vr0;  *(u16x8*)&Vs[q8b * 8] = vr1;
        __syncthreads();
        if (kt < 31) {                 // prefetch next tile (K rows +64, V cols +64)
            gK0 += 64 * HDIM; gK1 += 64 * HDIM; gV0 += 64; gV1 += 64;
            kr0 = *(const u16x8*)gK0; kr1 = *(const u16x8*)gK1;
            vr0 = *(const u16x8*)gV0; vr1 = *(const u16x8*)gV1;
        }

        // S^T[k' 64][q 32]: 2 mt-blocks x 4 hd-chunks
        f32x16 S[2];
#pragma unroll
        for (int mt = 0; mt < 2; ++mt) {
#pragma unroll
            for (int r = 0; r < 16; ++r) S[mt][r] = 0.f;
#pragma unroll
            for (int s = 0; s < 4; ++s) {
                bf16x8 af = *(const bf16x8*)&Ks[(mt * 4 + s) * 512 + half * 256 + ln31 * 8];
                S[mt] = __builtin_amdgcn_mfma_f32_32x32x16_bf16(af, qf[s], S[mt], 0, 0, 0);
            }
        }

        // online softmax: lane holds 32 S-values for its q; lane^32 holds the other 32 k'
        float mx = S[0][0];
#pragma unroll
        for (int mt = 0; mt < 2; ++mt)
#pragma unroll
            for (int r = 0; r < 16; ++r) mx = fmaxf(mx, S[mt][r]);
        mx = fmaxf(mx, __shfl_xor(mx, 32));
        float mn = fmaxf(m_run, mx);
        float alpha = __expf(m_run - mn);
        m_run = mn;
        float rs = 0.f;
#pragma unroll
        for (int mt = 0; mt < 2; ++mt)
#pragma unroll
            for (int r = 0; r < 16; ++r) {
                float p = __expf(S[mt][r] - mn);
                S[mt][r] = p;
                rs += p;
            }
        rs += __shfl_xor(rs, 32);
        l_run = l_run * alpha + rs;

        // P^T -> Ps (B-operand frag layout). C-layout row = (r&3)+8*(r>>2)+4*half (+32*mt):
        // pack r&3 quads -> b64 at frag (2mt+(rg>>1)), hf = rg&1, j0 = 4*half.
#pragma unroll
        for (int mt = 0; mt < 2; ++mt)
#pragma unroll
            for (int rg = 0; rg < 4; ++rg) {
                u16x4 pw = {f2bf(S[mt][rg * 4 + 0]), f2bf(S[mt][rg * 4 + 1]),
                            f2bf(S[mt][rg * 4 + 2]), f2bf(S[mt][rg * 4 + 3])};
                *(u16x4*)&PsW[(2 * mt + (rg >> 1)) * 512 + (rg & 1) * 256 + ln31 * 8 + half * 4] = pw;
            }

        // rescale O
#pragma unroll
        for (int mt = 0; mt < 2; ++mt)
#pragma unroll
            for (int r = 0; r < 16; ++r) Oacc[mt][r] *= alpha;

        // O^T[hd 64][q 32] += V^T . P^T   (same-wave LDS: compiler inserts lgkmcnt, no barrier)
#pragma unroll
        for (int sp = 0; sp < 4; ++sp) {
            bf16x8 bp = *(const bf16x8*)&PsW[sp * 512 + half * 256 + ln31 * 8];
#pragma unroll
            for (int mt = 0; mt < 2; ++mt) {
                bf16x8 av = *(const bf16x8*)&Vs[(mt * 4 + sp) * 512 + half * 256 + ln31 * 8];
                Oacc[mt] = __builtin_amdgcn_mfma_f32_32x32x16_bf16(av, bp, Oacc[mt], 0, 0, 0);
            }
        }
    }

    // epilogue: lane q = ln31, hd = mt*32 + 8*rg + 4*half + (r&3) -> b64 packed stores
    float inv = 1.f / l_run;
    int q = q0 + wave * 32 + ln31;
    unsigned short* orow = att + (size_t)(b * SEQ + q) * EMBED + h * HDIM;
#pragma unroll
    for (int mt = 0; mt < 2; ++mt)
#pragma unroll
        for (int rg = 0; rg < 4; ++rg) {
            u16x4 ow = {f2bf(Oacc[mt][rg * 4 + 0] * inv), f2bf(Oacc[mt][rg * 4 + 1] * inv),
                        f2bf(Oacc[mt][rg * 4 + 2] * inv), f2bf(Oacc[mt][rg * 4 + 3] * inv)};
            *(u16x4*)&orow[mt * 32 + rg * 8 + half * 4] = ow;
        }
}

// ---------------- row LayerNorm (one block per row) ----------------
__global__ __launch_bounds__(256) void ln_kernel(const float* __restrict__ x,
                                                 const float* __restrict__ gamma,
                                                 const float* __restrict__ beta,
                                                 float* __restrict__ out) {
    __shared__ float red[8];
    const int row = blockIdx.x, t = threadIdx.x;
    float4 v = *(const float4*)(x + (size_t)row * EMBED + t * 4);
    float s = v.x + v.y + v.z + v.w;
    float ss = v.x * v.x + v.y * v.y + v.z * v.z + v.w * v.w;
#pragma unroll
    for (int o = 1; o < 64; o <<= 1) {
        s += __shfl_xor(s, o);
        ss += __shfl_xor(ss, o);
    }
    int wave = t >> 6, lane = t & 63;
    if (lane == 0) { red[wave] = s; red[4 + wave] = ss; }
    __syncthreads();
    s = red[0] + red[1] + red[2] + red[3];
    ss = red[4] + red[5] + red[6] + red[7];
    float mu = s * (1.f / EMBED);
    float var = ss * (1.f / EMBED) - mu * mu;
    float rstd = rsqrtf(var + 1e-5f);
    float4 g = *(const float4*)(gamma + t * 4);
    float4 bb = *(const float4*)(beta + t * 4);
    float4 o;
    o.x = (v.x - mu) * rstd * g.x + bb.x;
    o.y = (v.y - mu) * rstd * g.y + bb.y;
    o.z = (v.z - mu) * rstd * g.z + bb.z;
    o.w = (v.w - mu) * rstd * g.w + bb.w;
    *(float4*)(out + (size_t)row * EMBED + t * 4) = o;
}

// ---------------- launch ----------------
extern "C" void kernel_launch(void* const* d_in, const int* in_sizes, int n_in,
                              void* d_out, int out_size, void* d_ws, size_t ws_size,
                              hipStream_t stream) {
    const float* query = (const float*)d_in[0];
    const float* key_  = (const float*)d_in[1];
    const float* value = (const float*)d_in[2];
    const float* Wq = (const float*)d_in[3];
    const float* bq = (const float*)d_in[4];
    const float* Wk = (const float*)d_in[5];
    const float* bk = (const float*)d_in[6];
    const float* Wv = (const float*)d_in[7];
    const float* bv = (const float*)d_in[8];
    const float* Wo = (const float*)d_in[9];
    const float* bo = (const float*)d_in[10];
    const float* gamma = (const float*)d_in[11];
    const float* beta  = (const float*)d_in[12];

    char* ws = (char*)d_ws;
    const size_t MB = 1024 * 1024;
    unsigned short* qb  = (unsigned short*)(ws + 0);
    unsigned short* kb  = (unsigned short*)(ws + 8 * MB);
    unsigned short* vb  = (unsigned short*)(ws + 16 * MB);
    unsigned short* Wqt = (unsigned short*)(ws + 24 * MB);
    unsigned short* Wkt = (unsigned short*)(ws + 26 * MB);
    unsigned short* Wvt = (unsigned short*)(ws + 28 * MB);
    unsigned short* Wot = (unsigned short*)(ws + 30 * MB);
    unsigned short* Qp  = (unsigned short*)(ws + 32 * MB);
    unsigned short* Kp  = (unsigned short*)(ws + 40 * MB);
    unsigned short* Vtb = (unsigned short*)(ws + 48 * MB);
    unsigned short* att = (unsigned short*)(ws + 0);        // aliases qb (dead after Q-proj)
    float*          xbuf = (float*)(ws + 8 * MB);           // aliases kb+vb (dead after K/V-proj)

    cvt3_kernel<<<dim3(4096, 3), 256, 0, stream>>>(query, key_, value, qb, kb, vb);
    transpose4_kernel<<<dim3(32, 32, 4), dim3(32, 8), 0, stream>>>(Wq, Wk, Wv, Wo, Wqt, Wkt, Wvt, Wot);

    gemm_qkv_kernel<<<dim3(8, 32, 3), 256, 0, stream>>>(qb, kb, vb, Wqt, Wkt, Wvt,
                                                        bq, bk, bv, Qp, Kp, Vtb);

    attn_kernel<<<dim3(32, 16), 256, 0, stream>>>(Qp, Kp, Vtb, att);

    gemm_o_kernel<<<dim3(8, 64), 256, 0, stream>>>(att, Wot, bo, xbuf, query);
    ln_kernel<<<ROWS, 256, 0, stream>>>(xbuf, gamma, beta, (float*)d_out);
}